// Round 9
// baseline (95.498 us; speedup 1.0000x reference)
//
#include <hip/hip_runtime.h>
#include <math.h>

typedef float v2f __attribute__((ext_vector_type(2)));

#define NSUP 512
#define DLAT 128
#define DHID 512
#define DIN  64
#define BR   16
#define NTILE 256   // 4096 / BR

// ---------------- prep: transposes + packs + interleaved support trig + norms ----------------
__global__ __launch_bounds__(512) void prep_kernel(
    const float* __restrict__ x, const float* __restrict__ W1, const float* __restrict__ W2,
    const float* __restrict__ support,
    float* __restrict__ W1T, float* __restrict__ W2T, float* __restrict__ xpack,
    float* __restrict__ scd3, float* __restrict__ sn2)
{
    int idx = blockIdx.x * 512 + threadIdx.x;          // 512 x 512 = 262144
    {   // xpack[t][k][r] = x[t*16+r][k]   (writes coalesced)
        int t = idx >> 10, rem = idx & 1023, k = rem >> 4, r = rem & 15;
        xpack[idx] = x[((t << 4) | r) * DIN + k];
    }
    if (idx < DHID * DIN) {                 // W1 [512][64] -> W1T [64][512]
        int c = idx / DIN, k = idx % DIN;
        W1T[k * DHID + c] = W1[idx];
    }
    if (idx < DLAT * DHID) {
        int j = idx / DHID, k = idx % DHID;             // W2 -> W2T
        W2T[k * DLAT + j] = W2[idx];
        int s = idx & (NSUP - 1), i = idx >> 9;         // scd3[i][s][3], 12B/lane coalesced
        float v = support[s * DLAT + i];
        int base = (i * NSUP + s) * 3;
        scd3[base]     = v;
        scd3[base + 1] = cosf(0.5f * v);
        scd3[base + 2] = sinf(0.5f * v);
    }
    if (idx < NSUP) {                       // ||s||^2 via float4
        const float4* sp = (const float4*)(support + idx * DLAT);
        float acc = 0.f;
        #pragma unroll 8
        for (int i4 = 0; i4 < DLAT / 4; i4++) {
            float4 v = sp[i4];
            acc = fmaf(v.x, v.x, fmaf(v.y, v.y, fmaf(v.z, v.z, fmaf(v.w, v.w, acc))));
        }
        sn2[idx] = acc;
    }
}

// ---------------- GEMM1: h = tanh(x @ W1^T + b1)  (s_load broadcast path) ----------------
__global__ __launch_bounds__(512) void gemm1_kernel(
    const float* __restrict__ W1T, const float* __restrict__ b1,
    const float* __restrict__ xpack, float* __restrict__ hpack)
{
    __shared__ float sh[DHID][17];                           // 34.8 KB
    const int t = blockIdx.x;
    const int c = threadIdx.x;
    const float* __restrict__ xr = xpack + t * (DIN * BR);   // uniform base -> s_load

    v2f acc[8];
    #pragma unroll
    for (int q = 0; q < 8; q++) acc[q] = (v2f)(0.f);

    for (int k = 0; k < DIN; k++) {
        float w = W1T[k * DHID + c];
        v2f wv = {w, w};
        const float* xk = xr + k * BR;                       // uniform -> s_load_dwordx16
        #pragma unroll
        for (int q = 0; q < 8; q++) {
            v2f xv = {xk[2 * q], xk[2 * q + 1]};
            acc[q] = __builtin_elementwise_fma(xv, wv, acc[q]);
        }
    }
    float bb = b1[c];
    #pragma unroll
    for (int q = 0; q < 8; q++) {
        sh[c][2 * q]     = tanhf(acc[q].x + bb);
        sh[c][2 * q + 1] = tanhf(acc[q].y + bb);
    }
    __syncthreads();
    float4* hp = (float4*)(hpack + t * (DHID * BR));
    #pragma unroll
    for (int w = threadIdx.x; w < DHID * BR / 4; w += 512) {
        int cc = w >> 2, r0 = (w & 3) * 4;
        hp[w] = make_float4(sh[cc][r0], sh[cc][r0 + 1], sh[cc][r0 + 2], sh[cc][r0 + 3]);
    }
}

// ---------------- GEMM2: latent + trig -> rowpack [t][i][rh][32]={l8|a8|b8|pad8} ----------------
__global__ __launch_bounds__(1024) void gemm2_kernel(
    const float* __restrict__ W2T, const float* __restrict__ b2,
    const float* __restrict__ hpack, float4* __restrict__ rowpack, float* __restrict__ ln2s)
{
    __shared__ float part[8][DLAT][17];    // 69632 B
    __shared__ float tbuf[DLAT][64];       // 32768 B transpose buffer
    __shared__ float l2red[16][2];

    const int t = blockIdx.x;
    const int j = threadIdx.x & (DLAT - 1);
    const int g = __builtin_amdgcn_readfirstlane(threadIdx.x >> 7);   // wave-uniform
    const float* __restrict__ hrow = hpack + t * (DHID * BR);

    v2f acc[8];
    #pragma unroll
    for (int q = 0; q < 8; q++) acc[q] = (v2f)(0.f);

    for (int kk = 0; kk < 64; kk++) {
        int k = g * 64 + kk;
        float w = W2T[k * DLAT + j];
        v2f wv = {w, w};
        const float* hk = hrow + k * BR;               // uniform -> s_load_dwordx16
        #pragma unroll
        for (int q = 0; q < 8; q++) {
            v2f hv = {hk[2 * q], hk[2 * q + 1]};
            acc[q] = __builtin_elementwise_fma(hv, wv, acc[q]);
        }
    }
    #pragma unroll
    for (int q = 0; q < 8; q++) {
        part[g][j][2 * q]     = acc[q].x;
        part[g][j][2 * q + 1] = acc[q].y;
    }
    __syncthreads();

    const int rp = g;                                   // row-pair 0..7, rows 2rp, 2rp+1
    float s0 = 0.f, s1 = 0.f;
    #pragma unroll
    for (int g2 = 0; g2 < 8; g2++) {
        s0 += part[g2][j][2 * rp];
        s1 += part[g2][j][2 * rp + 1];
    }
    float bb = b2[j];
    float l0 = s0 + bb, l1 = s1 + bb;

    // layout within tbuf[j]: [rh][ l8 | a8 | b8 | pad8 ], rh = rp>>2
    const int rh = rp >> 2, ro = (rp & 3) * 2;
    float* tb = &tbuf[j][rh * 32];
    tb[ro]          = l0;
    tb[ro + 1]      = l1;
    tb[8 + ro]      = cosf(0.5f * l0);
    tb[8 + ro + 1]  = cosf(0.5f * l1);
    tb[16 + ro]     = sinf(0.5f * l0);
    tb[16 + ro + 1] = sinf(0.5f * l1);
    tb[24 + ro]     = 0.f;                              // deterministic pad
    tb[24 + ro + 1] = 0.f;

    // ||l||^2 per row
    const int wv = threadIdx.x >> 6;
    float v0 = l0 * l0, v1 = l1 * l1;
    for (int off = 32; off; off >>= 1) { v0 += __shfl_down(v0, off); v1 += __shfl_down(v1, off); }
    if ((threadIdx.x & 63) == 0) { l2red[wv][0] = v0; l2red[wv][1] = v1; }
    __syncthreads();

    if (threadIdx.x < BR) {
        int r = threadIdx.x, p = r >> 1, sel = r & 1;
        ln2s[t * BR + r] = l2red[2 * p][sel] + l2red[2 * p + 1][sel];
    }
    // coalesced rowpack store: 128*64 floats = 2048 float4 per tile
    #pragma unroll
    for (int w = threadIdx.x; w < DLAT * 64 / 4; w += 1024) {
        int i = w >> 4, off = (w & 15) * 4;
        rowpack[t * 2048 + w] = make_float4(tbuf[i][off], tbuf[i][off + 1],
                                            tbuf[i][off + 2], tbuf[i][off + 3]);
    }
}

// ---------------- stage B: 8 rows x 1 sup per lane; rows via SMEM, sups via VMEM ----------------
// grid 1024 = 256 t x 4 sq. block 256 thr (4 waves), 4 blocks/CU -> 16 waves/CU.
// wave w: rh = w&1 (rows rh*8..rh*8+7), sg = w>>1; lane sup s = sq*128 + sg*64 + lane.
__global__ __launch_bounds__(256, 4) void kernelB(
    const float* __restrict__ scd3, const float* __restrict__ sn2,
    const float* __restrict__ wts, const float* __restrict__ rowpack,
    const float* __restrict__ ln2s, float* __restrict__ outpart)
{
    __shared__ float redw[4][8];

    const int b    = blockIdx.x;
    const int t    = b >> 2;
    const int sq   = b & 3;
    const int tid  = threadIdx.x;
    const int lane = tid & 63;
    const int wv   = __builtin_amdgcn_readfirstlane(tid >> 6);
    const int rh   = wv & 1;
    const int sg   = wv >> 1;
    const int s    = sq * 128 + sg * 64 + lane;       // one support per lane

    // uniform row base: [t][i][rh][32]
    const float* __restrict__ rp0 = rowpack + (t * DLAT * 2 + rh) * 32;
    const float* __restrict__ sp  = scd3 + s * 3;      // + i*1536

    v2f dot[4], prod[4];
    #pragma unroll
    for (int q = 0; q < 4; q++) { dot[q] = (v2f)(0.f); prod[q] = (v2f)(1.f); }

    #pragma unroll 2
    for (int i = 0; i < DLAT; i++) {
        const float* rp = rp0 + i * 64;               // uniform -> s_load_dwordx16 + x8
        float sv = sp[i * 1536];                      // per-lane 12B, coalesced
        float cv = sp[i * 1536 + 1];
        float nv = sp[i * 1536 + 2];
        v2f svv = {sv, sv}, cvv = {cv, cv}, nvv = {nv, nv};
        #pragma unroll
        for (int q = 0; q < 4; q++) {
            v2f lq = {rp[2 * q],      rp[2 * q + 1]};       // SGPR operands
            v2f aq = {rp[8 + 2 * q],  rp[8 + 2 * q + 1]};
            v2f bq = {rp[16 + 2 * q], rp[16 + 2 * q + 1]};
            dot[q] = __builtin_elementwise_fma(lq, svv, dot[q]);
            v2f tt = __builtin_elementwise_fma(aq, cvv, bq * nvv);
            prod[q] = prod[q] * tt;
        }
    }

    // ---- epilogue: kernels, weight, per-row reduce over this block's 128 sups ----
    float sn  = sn2[s];
    float wgt = wts[s];
    const float* lrp = ln2s + t * BR + rh * 8;        // uniform -> s_load_dwordx8
    float rowacc[8];
    #pragma unroll
    for (int r = 0; r < 8; r++) {
        float d = dot[r >> 1][r & 1];
        float p = prod[r >> 1][r & 1];
        float sq_ = lrp[r] + sn - 2.f * d;
        rowacc[r] = (0.5f * __expf(-sq_) + 0.5f * (p * p)) * wgt;
    }
    #pragma unroll
    for (int r = 0; r < 8; r++) {
        float v = rowacc[r];
        for (int off = 32; off; off >>= 1) v += __shfl_down(v, off);
        if (lane == 0) redw[wv][r] = v;
    }
    __syncthreads();
    if (tid < BR) {
        int rh2 = tid >> 3, r = tid & 7;              // row = rh2*8 + r
        outpart[sq * (NTILE * BR) + t * BR + tid] = redw[rh2][r] + redw[2 + rh2][r];
    }
}

// ---------------- combine: out = sum of 4 support-quarter partials ----------------
__global__ __launch_bounds__(256) void combine_kernel(
    const float* __restrict__ outpart, float* __restrict__ out)
{
    int i = blockIdx.x * 256 + threadIdx.x;           // 0..4095
    out[i] = (outpart[i] + outpart[NTILE * BR + i])
           + (outpart[2 * NTILE * BR + i] + outpart[3 * NTILE * BR + i]);
}

// ---------------- launch ----------------
extern "C" void kernel_launch(void* const* d_in, const int* in_sizes, int n_in,
                              void* d_out, int out_size, void* d_ws, size_t ws_size,
                              hipStream_t stream) {
    const float* x       = (const float*)d_in[0];
    const float* W1      = (const float*)d_in[1];
    const float* b1      = (const float*)d_in[2];
    const float* W2      = (const float*)d_in[3];
    const float* b2      = (const float*)d_in[4];
    const float* support = (const float*)d_in[5];
    const float* wts     = (const float*)d_in[6];
    float* out = (float*)d_out;

    float* ws      = (float*)d_ws;
    float* W1T     = ws;                        // 32768
    float* W2T     = W1T + 32768;               // 65536
    float* xpack   = W2T + 65536;               // 262144
    float* hpack   = xpack + 262144;            // 2097152   (16B-aligned offset)
    float* rowpack = hpack + 2097152;           // 2097152   (16B-aligned offset)
    float* ln2s    = rowpack + 2097152;         // 4096
    float* sn2     = ln2s + 4096;               // 512
    float* scd3    = sn2 + 512;                 // 196608 (16B-aligned offset)
    float* outpart = scd3 + 196608;             // 16384

    prep_kernel <<<512,  512, 0, stream>>>(x, W1, W2, support, W1T, W2T, xpack, scd3, sn2);
    gemm1_kernel<<<NTILE, 512, 0, stream>>>(W1T, b1, xpack, hpack);
    gemm2_kernel<<<NTILE, 1024, 0, stream>>>(W2T, b2, hpack, (float4*)rowpack, ln2s);
    kernelB     <<<NTILE * 4, 256, 0, stream>>>(scd3, sn2, wts, rowpack, ln2s, outpart);
    combine_kernel<<<16, 256, 0, stream>>>(outpart, out);
}